// Round 5
// baseline (3016.642 us; speedup 1.0000x reference)
//
#include <hip/hip_runtime.h>
#include <hip/hip_fp16.h>

// ---------------------------------------------------------------------------
// GenomeDecoder: tiny transformer -> 1028 sequential GRU steps -> chunks.
// Fused recurrence matrix M (1024x256 f16): chunk feedback folded in
// (x_t = out_W@h_t+out_b => A = Wih@out_W absorbed), r/z gate rows pre-summed.
// 16 CUs, one chain each.
// R5: matvec moved to the MFMA pipe (VALUBusy showed ~81% on active CUs with
// MfmaUtil 0 -> dot2-VALU was the cap).  mfma_f32_16x16x32_f16, B = h
// replicated across N (all output cols identical).  Wave w owns comps
// [w*32,w*32+32): all 4 gate rows of a comp land in the SAME lane/reg of 4
// accumulators -> per-lane combine, no gate exchange, 1 barrier/step.
// A-fragments: ks 0..5 register(AGPR)-resident, ks 6..7 streamed from LDS.
// ---------------------------------------------------------------------------

typedef _Float16 half8 __attribute__((ext_vector_type(8)));
typedef float f32x4 __attribute__((ext_vector_type(4)));
typedef unsigned int uint_t;

// ---- workspace layout (float indices) ----
static constexpr size_t WS_HB   = 0;
static constexpr size_t WS_QKV  = 65536;
static constexpr size_t WS_AO   = 262144;
static constexpr size_t WS_F1   = 327680;
static constexpr size_t WS_LAT  = 589824;
static constexpr size_t WS_GI0  = 593920;
static constexpr size_t WS_CV   = 606208;
static constexpr size_t WS_M    = 607232;   // 131072 dword slots (f16x2 packed)
static constexpr size_t WS_HSEQ = 738304;   // 1028*16*256 floats

__device__ inline float sigf(float x){ return 1.0f/(1.0f+__expf(-x)); }
__device__ inline float tanh_fast(float x){ float e=__expf(2.0f*x); return (e-1.0f)/(e+1.0f); }

// workgroup barrier WITHOUT vmcnt drain (LDS visibility only).
__device__ inline void bar_lgkm(){
    asm volatile("s_waitcnt lgkmcnt(0)\ns_barrier" ::: "memory");
}

// ======================= transformer front-end =============================

__global__ __launch_bounds__(256) void k_embed(const float* gs, const float* eW,
                                               const float* eb, float* ws){
    int bs = blockIdx.x;            // b*16+s
    int i  = threadIdx.x;
    const float* g = gs + bs*16;
    float acc = eb[i];
#pragma unroll
    for(int d=0; d<16; ++d) acc += g[d]*eW[i*16+d];
    ws[WS_HB + (size_t)bs*256 + i] = acc;
}

__global__ __launch_bounds__(256) void k_qkv(const float* qkvW, const float* qkvb,
                                             float* ws, int l){
    __shared__ float hr[16][256];
    int b = blockIdx.x, jc = blockIdx.y;
    for(int idx=threadIdx.x; idx<4096; idx+=256)
        hr[idx>>8][idx&255] = ws[WS_HB + (size_t)(b*16+(idx>>8))*256 + (idx&255)];
    __syncthreads();
    int j = jc*256 + threadIdx.x;
    float bias = qkvb[l*768 + j];
    float acc[16];
#pragma unroll
    for(int s=0;s<16;++s) acc[s]=bias;
    const float* wr = qkvW + (size_t)(l*768 + j)*256;
    for(int k=0;k<256;k+=4){
        float4 w4 = *(const float4*)(wr+k);
#pragma unroll
        for(int s=0;s<16;++s)
            acc[s] += w4.x*hr[s][k] + w4.y*hr[s][k+1] + w4.z*hr[s][k+2] + w4.w*hr[s][k+3];
    }
    for(int s=0;s<16;++s) ws[WS_QKV + (size_t)(b*16+s)*768 + j] = acc[s];
}

__global__ __launch_bounds__(256) void k_attn(float* ws){
    __shared__ float ql[16][64], kl[16][64], vl[16][64], sc[16][16];
    int b = blockIdx.x>>2, hh = blockIdx.x&3;
    for(int idx=threadIdx.x; idx<1024; idx+=256){
        int s_=idx>>6, d=idx&63;
        const float* base = &ws[WS_QKV + (size_t)(b*16+s_)*768 + hh*64 + d];
        ql[s_][d]=base[0]; kl[s_][d]=base[256]; vl[s_][d]=base[512];
    }
    __syncthreads();
    int s = threadIdx.x>>4, t = threadIdx.x&15;
    float a=0.f;
#pragma unroll
    for(int d=0; d<64; ++d) a += ql[s][d]*kl[t][d];
    sc[s][t] = a*0.125f;
    __syncthreads();
    if(threadIdx.x<16){
        int r=threadIdx.x;
        float m=-1e30f;
#pragma unroll
        for(int tt=0;tt<16;++tt) m=fmaxf(m,sc[r][tt]);
        float e[16]; float sum=0.f;
#pragma unroll
        for(int tt=0;tt<16;++tt){ e[tt]=__expf(sc[r][tt]-m); sum+=e[tt]; }
        float inv=1.0f/sum;
#pragma unroll
        for(int tt=0;tt<16;++tt) sc[r][tt]=e[tt]*inv;
    }
    __syncthreads();
    int dg = (threadIdx.x&15)*4;
#pragma unroll
    for(int dd=0;dd<4;++dd){
        int d = dg+dd; float o=0.f;
#pragma unroll
        for(int tt=0;tt<16;++tt) o += sc[s][tt]*vl[tt][d];
        ws[WS_AO + (size_t)(b*16+s)*256 + hh*64 + d] = o;
    }
}

__global__ __launch_bounds__(256) void k_ao_ln(const float* aoW, const float* aob,
                                               const float* g1, const float* b1,
                                               float* ws, int l){
    __shared__ float ao[256]; __shared__ float red[256];
    int bs = blockIdx.x, i = threadIdx.x;
    ao[i] = ws[WS_AO + (size_t)bs*256 + i];
    __syncthreads();
    const float* wr = aoW + (size_t)(l*256+i)*256;
    float acc = aob[l*256+i];
    for(int k=0;k<256;k+=4){
        float4 w4 = *(const float4*)(wr+k);
        acc += w4.x*ao[k]+w4.y*ao[k+1]+w4.z*ao[k+2]+w4.w*ao[k+3];
    }
    float x = ws[WS_HB + (size_t)bs*256 + i] + acc;
    red[i]=x; __syncthreads();
    for(int off=128;off>0;off>>=1){ if(i<off) red[i]+=red[i+off]; __syncthreads(); }
    float m = red[0]*(1.0f/256.0f); __syncthreads();
    float d = x-m;
    red[i]=d*d; __syncthreads();
    for(int off=128;off>0;off>>=1){ if(i<off) red[i]+=red[i+off]; __syncthreads(); }
    float v = red[0]*(1.0f/256.0f);
    float y = d / sqrtf(v+1e-5f);
    ws[WS_HB + (size_t)bs*256 + i] = y*g1[l*256+i] + b1[l*256+i];
}

__global__ __launch_bounds__(256) void k_ffn1(const float* W1, const float* fb1,
                                              float* ws, int l){
    __shared__ float hr[16][256];
    int b = blockIdx.x, jc = blockIdx.y;
    for(int idx=threadIdx.x; idx<4096; idx+=256)
        hr[idx>>8][idx&255] = ws[WS_HB + (size_t)(b*16+(idx>>8))*256 + (idx&255)];
    __syncthreads();
    int j = jc*256 + threadIdx.x;
    float bias = fb1[l*1024+j];
    float acc[16];
#pragma unroll
    for(int s=0;s<16;++s) acc[s]=bias;
    const float* wr = W1 + (size_t)(l*1024+j)*256;
    for(int k=0;k<256;k+=4){
        float4 w4 = *(const float4*)(wr+k);
#pragma unroll
        for(int s=0;s<16;++s)
            acc[s] += w4.x*hr[s][k] + w4.y*hr[s][k+1] + w4.z*hr[s][k+2] + w4.w*hr[s][k+3];
    }
    for(int s=0;s<16;++s)
        ws[WS_F1 + (size_t)(b*16+s)*1024 + j] = fmaxf(acc[s],0.0f);
}

__global__ __launch_bounds__(256) void k_ffn2_ln(const float* W2, const float* fb2,
                                                 const float* g2, const float* b2v,
                                                 float* ws, int l){
    __shared__ float f1r[1024]; __shared__ float red[256];
    int bs = blockIdx.x, i = threadIdx.x;
    for(int idx=i; idx<1024; idx+=256) f1r[idx] = ws[WS_F1 + (size_t)bs*1024 + idx];
    __syncthreads();
    const float* wr = W2 + (size_t)(l*256+i)*1024;
    float acc = fb2[l*256+i];
    for(int k=0;k<1024;k+=4){
        float4 w4 = *(const float4*)(wr+k);
        acc += w4.x*f1r[k]+w4.y*f1r[k+1]+w4.z*f1r[k+2]+w4.w*f1r[k+3];
    }
    float x = ws[WS_HB + (size_t)bs*256 + i] + acc;
    red[i]=x; __syncthreads();
    for(int off=128;off>0;off>>=1){ if(i<off) red[i]+=red[i+off]; __syncthreads(); }
    float m = red[0]*(1.0f/256.0f); __syncthreads();
    float d = x-m;
    red[i]=d*d; __syncthreads();
    for(int off=128;off>0;off>>=1){ if(i<off) red[i]+=red[i+off]; __syncthreads(); }
    float v = red[0]*(1.0f/256.0f);
    float y = d / sqrtf(v+1e-5f);
    ws[WS_HB + (size_t)bs*256 + i] = y*g2[l*256+i] + b2v[l*256+i];
}

__global__ __launch_bounds__(256) void k_latent(float* ws){
    int b=blockIdx.x, i=threadIdx.x; float a=0.f;
#pragma unroll
    for(int s=0;s<16;++s) a += ws[WS_HB + (size_t)(b*16+s)*256 + i];
    ws[WS_LAT + (size_t)b*256 + i] = a*(1.0f/16.0f);
}

// ======================= GRU prep ==========================================

__global__ __launch_bounds__(768) void k_gi0(const float* Wih, const float* bih,
                                             float* ws){
    __shared__ float lat[256];
    int b=blockIdx.x, j=threadIdx.x;
    if(j<256) lat[j]=ws[WS_LAT + (size_t)b*256 + j];
    __syncthreads();
    const float* wr = Wih + (size_t)j*256;
    float acc = bih[j];
    for(int k=0;k<256;k+=4){
        float4 w4=*(const float4*)(wr+k);
        acc += w4.x*lat[k]+w4.y*lat[k+1]+w4.z*lat[k+2]+w4.w*lat[k+3];
    }
    ws[WS_GI0 + (size_t)b*768 + j] = acc;
}

// Fused matrix M (1024x256) rows:  0..255 r-gate (A+Whh), 256..511 z-gate
// (A+Whh), 512..767 A_n, 768..1023 Whh_n ; A = Wih @ out_W.
__global__ __launch_bounds__(256) void k_prepm(const float* Wih, const float* Whh,
                                               const float* bih, const float* bhh,
                                               const float* outW, const float* outb,
                                               float* ws){
    __shared__ float wrow[256]; __shared__ float red[256]; __shared__ float mrow[256];
    int r=blockIdx.x, c=threadIdx.x;
    bool hasA = (r<768);
    wrow[c] = hasA ? Wih[(size_t)r*256+c] : 0.0f;
    __syncthreads();
    float m;
    if(hasA){
        float a=0.f;
        for(int k=0;k<256;++k) a += wrow[k]*outW[(size_t)k*256+c];
        if(r<512) a += Whh[(size_t)r*256+c];
        m=a;
    } else {
        m = Whh[(size_t)(r-256)*256+c];
    }
    mrow[c]=m;
    red[c] = wrow[c]*outb[c];
    __syncthreads();
    for(int off=128;off>0;off>>=1){ if(c<off) red[c]+=red[c+off]; __syncthreads(); }
    if(c==0){
        float cv;
        if(r<512)       cv = red[0] + bih[r] + bhh[r];
        else if(r<768)  cv = red[0] + bih[r];
        else            cv = bhh[r-256];
        ws[WS_CV + r] = cv;
    }
    if(c<128){
        union{ _Float16 h[2]; uint_t u; } pk;
        pk.h[0]=(_Float16)mrow[2*c]; pk.h[1]=(_Float16)mrow[2*c+1];
        ((uint_t*)(ws))[WS_M + (size_t)r*128 + c] = pk.u;
    }
}

// ======================= sequential GRU chain (MFMA) =======================
// 16 blocks, 512 threads (8 waves).  Wave w owns comps [w*32, w*32+32).
// Tiles (g=gate 0..3, hh=half 0..1): rows g*256 + w*32 + hh*16 .. +15.
// A-frag (16x16x32 f16): lane L holds A[m=L&15][k=(L>>4)*8+j], i.e. 16B at
// M[row = base+(L&15)][k = ks*32+(L>>4)*8].  B = h replicated over n:
// lane L holds h[ks*32+(L>>4)*8+j] -> 16B broadcast read from h16 LDS.
// C/D: D[row=(L>>4)*4+reg][col=L&15]; cols identical (B replicated), so every
// lane holds valid results for comps cb = w*32+hh*16+(L>>4)*4+reg.
// Gate combine is per-lane VALU over 4 accumulators.  1 barrier/step.

__global__ __launch_bounds__(512,2) void k_chain(const float* bhh, float* ws){
    __shared__ half8 wlds[2][8][512];          // ks=6,7 A-frags, per-lane: 128 KB
    __shared__ unsigned short h16b[2][256];    // double-buffered h (f16)
    __shared__ float cvf[1024];                // gate constants
    int tid = threadIdx.x, chain = blockIdx.x;
    int w = tid>>6, lane = tid&63, q16 = lane>>4, mrow = lane&15;
    const uint_t* Mdw = (const uint_t*)ws + WS_M;

    // register-resident A-fragments, ks = 0..5  (192 dwords/lane -> AGPRs)
    half8 wreg[4][2][6];
#pragma unroll
    for(int g=0; g<4; ++g)
#pragma unroll
    for(int hh=0; hh<2; ++hh){
        size_t row = (size_t)g*256 + (size_t)w*32 + (size_t)hh*16 + mrow;
#pragma unroll
        for(int ks=0; ks<6; ++ks)
            wreg[g][hh][ks] = *(const half8*)(Mdw + row*128 + ks*16 + q16*4);
    }
    // streamed A-fragments ks=6,7 -> LDS in per-lane layout (conflict-free)
#pragma unroll
    for(int s=0; s<2; ++s)
#pragma unroll
    for(int t8=0; t8<8; ++t8){
        int g = t8>>1, hh = t8&1;
        size_t row = (size_t)g*256 + (size_t)w*32 + (size_t)hh*16 + mrow;
        wlds[s][t8][tid] = *(const half8*)(Mdw + row*128 + (6+s)*16 + q16*4);
    }
    for(int idx=tid; idx<1024; idx+=512) cvf[idx] = ws[WS_CV + idx];

    // ---- step 0: h0 = 0, x0 = latent -> gh = bhh.  All lanes compute the
    // same comps as their col-0 representative (no divergence).
    const float* gi = ws + WS_GI0 + (size_t)chain*768;
    float hprev[2][4];
#pragma unroll
    for(int hh=0; hh<2; ++hh){
        int cb = w*32 + hh*16 + q16*4;
#pragma unroll
        for(int r=0; r<4; ++r){
            int c = cb + r;
            float r0 = sigf(gi[c] + bhh[c]);
            float z0 = sigf(gi[256+c] + bhh[256+c]);
            float n0 = tanh_fast(gi[512+c] + r0*bhh[512+c]);
            hprev[hh][r] = (1.0f - z0)*n0;
        }
        if(mrow==0){
            union{ _Float16 h[4]; uint2 u; } pk;
#pragma unroll
            for(int r=0;r<4;++r) pk.h[r] = (_Float16)hprev[hh][r];
            *(uint2*)&h16b[0][cb] = pk.u;
            f32x4 st = {hprev[hh][0], hprev[hh][1], hprev[hh][2], hprev[hh][3]};
            *(f32x4*)&ws[WS_HSEQ + (size_t)chain*256 + cb] = st;
        }
    }
    __syncthreads();   // staging + step-0 h visible

    for(int t=1; t<1028; ++t){
        int p = (t-1)&1;
        const char* hbase = (const char*)&h16b[p][0];
#pragma unroll
        for(int hh=0; hh<2; ++hh){
            f32x4 a0={0.f,0.f,0.f,0.f}, a1=a0, a2=a0, a3=a0;
#pragma unroll
            for(int ks=0; ks<8; ++ks){
                half8 hv = *(const half8*)(hbase + ks*64 + q16*16);
                half8 m0 = (ks<6) ? wreg[0][hh][ks] : wlds[ks-6][0*2+hh][tid];
                half8 m1 = (ks<6) ? wreg[1][hh][ks] : wlds[ks-6][1*2+hh][tid];
                half8 m2 = (ks<6) ? wreg[2][hh][ks] : wlds[ks-6][2*2+hh][tid];
                half8 m3 = (ks<6) ? wreg[3][hh][ks] : wlds[ks-6][3*2+hh][tid];
                a0 = __builtin_amdgcn_mfma_f32_16x16x32_f16(m0, hv, a0, 0,0,0);
                a1 = __builtin_amdgcn_mfma_f32_16x16x32_f16(m1, hv, a1, 0,0,0);
                a2 = __builtin_amdgcn_mfma_f32_16x16x32_f16(m2, hv, a2, 0,0,0);
                a3 = __builtin_amdgcn_mfma_f32_16x16x32_f16(m3, hv, a3, 0,0,0);
            }
            int cb = w*32 + hh*16 + q16*4;
            f32x4 cr = *(const f32x4*)&cvf[cb];
            f32x4 cz = *(const f32x4*)&cvf[256+cb];
            f32x4 cn = *(const f32x4*)&cvf[512+cb];
            f32x4 cw = *(const f32x4*)&cvf[768+cb];
#pragma unroll
            for(int r=0; r<4; ++r){
                float rr = sigf(a0[r] + cr[r]);
                float zz = sigf(a1[r] + cz[r]);
                float nn = tanh_fast(a2[r] + cn[r] + rr*(a3[r] + cw[r]));
                hprev[hh][r] = (1.0f - zz)*nn + zz*hprev[hh][r];
            }
            if(mrow==0){
                union{ _Float16 h[4]; uint2 u; } pk;
#pragma unroll
                for(int r=0;r<4;++r) pk.h[r] = (_Float16)hprev[hh][r];
                *(uint2*)&h16b[p^1][cb] = pk.u;
                f32x4 st = {hprev[hh][0], hprev[hh][1], hprev[hh][2], hprev[hh][3]};
                *(f32x4*)&ws[WS_HSEQ + ((size_t)t*16 + chain)*256 + cb] = st;
            }
        }
        bar_lgkm();   // new h visible; HSEQ stores ride the vmcnt queue
    }
}

// ======================= epilogue GEMM =====================================
// OUT[b][t*256+j] = sum_c out_W[j][c]*HSEQ[t][b][c] + out_b[j]
__global__ __launch_bounds__(256) void k_epi(const float* outW, const float* outb,
                                             const float* ws, float* out){
    __shared__ float ht[16][256];
    int t = blockIdx.x, j = threadIdx.x;
    for(int idx=j; idx<4096; idx+=256)
        ht[idx>>8][idx&255] = ws[WS_HSEQ + (size_t)t*4096 + idx];
    __syncthreads();
    const float* wr = outW + (size_t)j*256;
    float bias = outb[j];
    float acc[16];
#pragma unroll
    for(int bb=0;bb<16;++bb) acc[bb]=bias;
    for(int k=0;k<256;k+=4){
        float4 w4 = *(const float4*)(wr+k);
#pragma unroll
        for(int bb=0;bb<16;++bb)
            acc[bb] += w4.x*ht[bb][k]+w4.y*ht[bb][k+1]+w4.z*ht[bb][k+2]+w4.w*ht[bb][k+3];
    }
#pragma unroll
    for(int bb=0;bb<16;++bb)
        out[(size_t)bb*263168 + (size_t)t*256 + j] = acc[bb];
}

// ======================= launch ============================================

extern "C" void kernel_launch(void* const* d_in, const int* in_sizes, int n_in,
                              void* d_out, int out_size, void* d_ws, size_t ws_size,
                              hipStream_t stream){
    const float* gs   = (const float*)d_in[0];
    const float* eW   = (const float*)d_in[1];
    const float* eb   = (const float*)d_in[2];
    const float* qkvW = (const float*)d_in[3];
    const float* qkvb = (const float*)d_in[4];
    const float* aoW  = (const float*)d_in[5];
    const float* aob  = (const float*)d_in[6];
    const float* g1   = (const float*)d_in[7];
    const float* b1   = (const float*)d_in[8];
    const float* g2   = (const float*)d_in[9];
    const float* b2   = (const float*)d_in[10];
    const float* W1   = (const float*)d_in[11];
    const float* fb1  = (const float*)d_in[12];
    const float* W2   = (const float*)d_in[13];
    const float* fb2  = (const float*)d_in[14];
    const float* Wih  = (const float*)d_in[15];
    const float* Whh  = (const float*)d_in[16];
    const float* bih  = (const float*)d_in[17];
    const float* bhh  = (const float*)d_in[18];
    const float* outW = (const float*)d_in[19];
    const float* outb = (const float*)d_in[20];
    float* ws  = (float*)d_ws;
    float* out = (float*)d_out;

    k_embed<<<256,256,0,stream>>>(gs,eW,eb,ws);
    for(int l=0;l<2;++l){
        k_qkv    <<<dim3(16,3),256,0,stream>>>(qkvW,qkvb,ws,l);
        k_attn   <<<64,256,0,stream>>>(ws);
        k_ao_ln  <<<256,256,0,stream>>>(aoW,aob,g1,b1,ws,l);
        k_ffn1   <<<dim3(16,4),256,0,stream>>>(W1,fb1,ws,l);
        k_ffn2_ln<<<256,256,0,stream>>>(W2,fb2,g2,b2,ws,l);
    }
    k_latent<<<16,256,0,stream>>>(ws);
    k_gi0   <<<16,768,0,stream>>>(Wih,bih,ws);
    k_prepm <<<1024,256,0,stream>>>(Wih,Whh,bih,bhh,outW,outb,ws);
    k_chain <<<16,512,0,stream>>>(bhh,ws);
    k_epi   <<<1028,256,0,stream>>>(outW,outb,ws,out);
}

// Round 6
// 2191.006 us; speedup vs baseline: 1.3768x; 1.3768x over previous
//
#include <hip/hip_runtime.h>
#include <hip/hip_fp16.h>

// ---------------------------------------------------------------------------
// GenomeDecoder: tiny transformer -> 1028 sequential GRU steps -> chunks.
// Fused recurrence matrix M (1024x256 f16): chunk feedback folded in
// (x_t = out_W@h_t+out_b => A = Wih@out_W absorbed), r/z gate rows pre-summed.
// 16 CUs, one chain each.  MFMA matvec (R5 layouts, correctness-verified).
// R6: kill the two VALU sinks R5's counters exposed:
//  (1) per-lane DEDUP of the gate combine (16 lanes of a q16 group hold
//      identical replicated cols): lane mrow selects row mrow&3 via cndmask,
//      computes ONE combine per hh (6 trans vs 48), stores mrow<4.
//  (2) register pressure < 256/lane (hh-serial acc, cvf array deleted,
//      hprev 8->2) so wreg lives in AGPRs as direct MFMA A-operands, no
//      allocator shuttle copies.
// ---------------------------------------------------------------------------

typedef _Float16 half8 __attribute__((ext_vector_type(8)));
typedef float f32x4 __attribute__((ext_vector_type(4)));
typedef unsigned int uint_t;

// ---- workspace layout (float indices) ----
static constexpr size_t WS_HB   = 0;
static constexpr size_t WS_QKV  = 65536;
static constexpr size_t WS_AO   = 262144;
static constexpr size_t WS_F1   = 327680;
static constexpr size_t WS_LAT  = 589824;
static constexpr size_t WS_GI0  = 593920;
static constexpr size_t WS_CV   = 606208;
static constexpr size_t WS_M    = 607232;   // 131072 dword slots (f16x2 packed)
static constexpr size_t WS_HSEQ = 738304;   // 1028*16*256 floats

__device__ inline float sigf(float x){ return 1.0f/(1.0f+__expf(-x)); }
__device__ inline float tanh_fast(float x){ float e=__expf(2.0f*x); return (e-1.0f)/(e+1.0f); }

__device__ inline unsigned short f2hb(float x){
    union{ _Float16 h; unsigned short u; } c; c.h = (_Float16)x; return c.u;
}

// workgroup barrier WITHOUT vmcnt drain (LDS visibility only).
__device__ inline void bar_lgkm(){
    asm volatile("s_waitcnt lgkmcnt(0)\ns_barrier" ::: "memory");
}

// ======================= transformer front-end =============================

__global__ __launch_bounds__(256) void k_embed(const float* gs, const float* eW,
                                               const float* eb, float* ws){
    int bs = blockIdx.x;            // b*16+s
    int i  = threadIdx.x;
    const float* g = gs + bs*16;
    float acc = eb[i];
#pragma unroll
    for(int d=0; d<16; ++d) acc += g[d]*eW[i*16+d];
    ws[WS_HB + (size_t)bs*256 + i] = acc;
}

__global__ __launch_bounds__(256) void k_qkv(const float* qkvW, const float* qkvb,
                                             float* ws, int l){
    __shared__ float hr[16][256];
    int b = blockIdx.x, jc = blockIdx.y;
    for(int idx=threadIdx.x; idx<4096; idx+=256)
        hr[idx>>8][idx&255] = ws[WS_HB + (size_t)(b*16+(idx>>8))*256 + (idx&255)];
    __syncthreads();
    int j = jc*256 + threadIdx.x;
    float bias = qkvb[l*768 + j];
    float acc[16];
#pragma unroll
    for(int s=0;s<16;++s) acc[s]=bias;
    const float* wr = qkvW + (size_t)(l*768 + j)*256;
    for(int k=0;k<256;k+=4){
        float4 w4 = *(const float4*)(wr+k);
#pragma unroll
        for(int s=0;s<16;++s)
            acc[s] += w4.x*hr[s][k] + w4.y*hr[s][k+1] + w4.z*hr[s][k+2] + w4.w*hr[s][k+3];
    }
    for(int s=0;s<16;++s) ws[WS_QKV + (size_t)(b*16+s)*768 + j] = acc[s];
}

__global__ __launch_bounds__(256) void k_attn(float* ws){
    __shared__ float ql[16][64], kl[16][64], vl[16][64], sc[16][16];
    int b = blockIdx.x>>2, hh = blockIdx.x&3;
    for(int idx=threadIdx.x; idx<1024; idx+=256){
        int s_=idx>>6, d=idx&63;
        const float* base = &ws[WS_QKV + (size_t)(b*16+s_)*768 + hh*64 + d];
        ql[s_][d]=base[0]; kl[s_][d]=base[256]; vl[s_][d]=base[512];
    }
    __syncthreads();
    int s = threadIdx.x>>4, t = threadIdx.x&15;
    float a=0.f;
#pragma unroll
    for(int d=0; d<64; ++d) a += ql[s][d]*kl[t][d];
    sc[s][t] = a*0.125f;
    __syncthreads();
    if(threadIdx.x<16){
        int r=threadIdx.x;
        float m=-1e30f;
#pragma unroll
        for(int tt=0;tt<16;++tt) m=fmaxf(m,sc[r][tt]);
        float e[16]; float sum=0.f;
#pragma unroll
        for(int tt=0;tt<16;++tt){ e[tt]=__expf(sc[r][tt]-m); sum+=e[tt]; }
        float inv=1.0f/sum;
#pragma unroll
        for(int tt=0;tt<16;++tt) sc[r][tt]=e[tt]*inv;
    }
    __syncthreads();
    int dg = (threadIdx.x&15)*4;
#pragma unroll
    for(int dd=0;dd<4;++dd){
        int d = dg+dd; float o=0.f;
#pragma unroll
        for(int tt=0;tt<16;++tt) o += sc[s][tt]*vl[tt][d];
        ws[WS_AO + (size_t)(b*16+s)*256 + hh*64 + d] = o;
    }
}

__global__ __launch_bounds__(256) void k_ao_ln(const float* aoW, const float* aob,
                                               const float* g1, const float* b1,
                                               float* ws, int l){
    __shared__ float ao[256]; __shared__ float red[256];
    int bs = blockIdx.x, i = threadIdx.x;
    ao[i] = ws[WS_AO + (size_t)bs*256 + i];
    __syncthreads();
    const float* wr = aoW + (size_t)(l*256+i)*256;
    float acc = aob[l*256+i];
    for(int k=0;k<256;k+=4){
        float4 w4 = *(const float4*)(wr+k);
        acc += w4.x*ao[k]+w4.y*ao[k+1]+w4.z*ao[k+2]+w4.w*ao[k+3];
    }
    float x = ws[WS_HB + (size_t)bs*256 + i] + acc;
    red[i]=x; __syncthreads();
    for(int off=128;off>0;off>>=1){ if(i<off) red[i]+=red[i+off]; __syncthreads(); }
    float m = red[0]*(1.0f/256.0f); __syncthreads();
    float d = x-m;
    red[i]=d*d; __syncthreads();
    for(int off=128;off>0;off>>=1){ if(i<off) red[i]+=red[i+off]; __syncthreads(); }
    float v = red[0]*(1.0f/256.0f);
    float y = d / sqrtf(v+1e-5f);
    ws[WS_HB + (size_t)bs*256 + i] = y*g1[l*256+i] + b1[l*256+i];
}

__global__ __launch_bounds__(256) void k_ffn1(const float* W1, const float* fb1,
                                              float* ws, int l){
    __shared__ float hr[16][256];
    int b = blockIdx.x, jc = blockIdx.y;
    for(int idx=threadIdx.x; idx<4096; idx+=256)
        hr[idx>>8][idx&255] = ws[WS_HB + (size_t)(b*16+(idx>>8))*256 + (idx&255)];
    __syncthreads();
    int j = jc*256 + threadIdx.x;
    float bias = fb1[l*1024+j];
    float acc[16];
#pragma unroll
    for(int s=0;s<16;++s) acc[s]=bias;
    const float* wr = W1 + (size_t)(l*1024+j)*256;
    for(int k=0;k<256;k+=4){
        float4 w4 = *(const float4*)(wr+k);
#pragma unroll
        for(int s=0;s<16;++s)
            acc[s] += w4.x*hr[s][k] + w4.y*hr[s][k+1] + w4.z*hr[s][k+2] + w4.w*hr[s][k+3];
    }
    for(int s=0;s<16;++s)
        ws[WS_F1 + (size_t)(b*16+s)*1024 + j] = fmaxf(acc[s],0.0f);
}

__global__ __launch_bounds__(256) void k_ffn2_ln(const float* W2, const float* fb2,
                                                 const float* g2, const float* b2v,
                                                 float* ws, int l){
    __shared__ float f1r[1024]; __shared__ float red[256];
    int bs = blockIdx.x, i = threadIdx.x;
    for(int idx=i; idx<1024; idx+=256) f1r[idx] = ws[WS_F1 + (size_t)bs*1024 + idx];
    __syncthreads();
    const float* wr = W2 + (size_t)(l*256+i)*1024;
    float acc = fb2[l*256+i];
    for(int k=0;k<1024;k+=4){
        float4 w4 = *(const float4*)(wr+k);
        acc += w4.x*f1r[k]+w4.y*f1r[k+1]+w4.z*f1r[k+2]+w4.w*f1r[k+3];
    }
    float x = ws[WS_HB + (size_t)bs*256 + i] + acc;
    red[i]=x; __syncthreads();
    for(int off=128;off>0;off>>=1){ if(i<off) red[i]+=red[i+off]; __syncthreads(); }
    float m = red[0]*(1.0f/256.0f); __syncthreads();
    float d = x-m;
    red[i]=d*d; __syncthreads();
    for(int off=128;off>0;off>>=1){ if(i<off) red[i]+=red[i+off]; __syncthreads(); }
    float v = red[0]*(1.0f/256.0f);
    float y = d / sqrtf(v+1e-5f);
    ws[WS_HB + (size_t)bs*256 + i] = y*g2[l*256+i] + b2v[l*256+i];
}

__global__ __launch_bounds__(256) void k_latent(float* ws){
    int b=blockIdx.x, i=threadIdx.x; float a=0.f;
#pragma unroll
    for(int s=0;s<16;++s) a += ws[WS_HB + (size_t)(b*16+s)*256 + i];
    ws[WS_LAT + (size_t)b*256 + i] = a*(1.0f/16.0f);
}

// ======================= GRU prep ==========================================

__global__ __launch_bounds__(768) void k_gi0(const float* Wih, const float* bih,
                                             float* ws){
    __shared__ float lat[256];
    int b=blockIdx.x, j=threadIdx.x;
    if(j<256) lat[j]=ws[WS_LAT + (size_t)b*256 + j];
    __syncthreads();
    const float* wr = Wih + (size_t)j*256;
    float acc = bih[j];
    for(int k=0;k<256;k+=4){
        float4 w4=*(const float4*)(wr+k);
        acc += w4.x*lat[k]+w4.y*lat[k+1]+w4.z*lat[k+2]+w4.w*lat[k+3];
    }
    ws[WS_GI0 + (size_t)b*768 + j] = acc;
}

// Fused matrix M (1024x256) rows:  0..255 r-gate (A+Whh), 256..511 z-gate
// (A+Whh), 512..767 A_n, 768..1023 Whh_n ; A = Wih @ out_W.
__global__ __launch_bounds__(256) void k_prepm(const float* Wih, const float* Whh,
                                               const float* bih, const float* bhh,
                                               const float* outW, const float* outb,
                                               float* ws){
    __shared__ float wrow[256]; __shared__ float red[256]; __shared__ float mrow[256];
    int r=blockIdx.x, c=threadIdx.x;
    bool hasA = (r<768);
    wrow[c] = hasA ? Wih[(size_t)r*256+c] : 0.0f;
    __syncthreads();
    float m;
    if(hasA){
        float a=0.f;
        for(int k=0;k<256;++k) a += wrow[k]*outW[(size_t)k*256+c];
        if(r<512) a += Whh[(size_t)r*256+c];
        m=a;
    } else {
        m = Whh[(size_t)(r-256)*256+c];
    }
    mrow[c]=m;
    red[c] = wrow[c]*outb[c];
    __syncthreads();
    for(int off=128;off>0;off>>=1){ if(c<off) red[c]+=red[c+off]; __syncthreads(); }
    if(c==0){
        float cv;
        if(r<512)       cv = red[0] + bih[r] + bhh[r];
        else if(r<768)  cv = red[0] + bih[r];
        else            cv = bhh[r-256];
        ws[WS_CV + r] = cv;
    }
    if(c<128){
        union{ _Float16 h[2]; uint_t u; } pk;
        pk.h[0]=(_Float16)mrow[2*c]; pk.h[1]=(_Float16)mrow[2*c+1];
        ((uint_t*)(ws))[WS_M + (size_t)r*128 + c] = pk.u;
    }
}

// ======================= sequential GRU chain (MFMA, dedup) ================
// 16 blocks, 512 threads (8 waves).  Wave w owns comps [w*32, w*32+32).
// Tiles (g=gate, hh=half): rows g*256 + w*32 + hh*16 + mrow; A-frag layout
// and B=h-replication as R5 (correctness-verified).  After MFMA, cols are
// replicated across the 16 lanes of a q16 group; lane mrow selects acc row
// rsel=mrow&3 via 3 cndmask/gate and computes ONE gate combine per hh;
// stores predicated mrow<4 (4 mrow x 4 q16 = 16 comps per wave per hh).

__global__ __launch_bounds__(512,2) void k_chain(const float* bhh, float* ws){
    __shared__ half8 wlds[2][8][512];          // ks=6,7 A-frags: 128 KB
    __shared__ unsigned short h16b[2][256];    // double-buffered h (f16)
    int tid = threadIdx.x, chain = blockIdx.x;
    int w = tid>>6, lane = tid&63, q16 = lane>>4, mrow = lane&15;
    int rsel = mrow & 3;
    const uint_t* Mdw = (const uint_t*)ws + WS_M;

    // register(AGPR)-resident A-fragments, ks = 0..5  (192 dwords/lane)
    half8 wreg[4][2][6];
#pragma unroll
    for(int g=0; g<4; ++g)
#pragma unroll
    for(int hh=0; hh<2; ++hh){
        size_t row = (size_t)g*256 + (size_t)w*32 + (size_t)hh*16 + mrow;
#pragma unroll
        for(int ks=0; ks<6; ++ks)
            wreg[g][hh][ks] = *(const half8*)(Mdw + row*128 + ks*16 + q16*4);
    }
    // streamed A-fragments ks=6,7 -> LDS in per-lane layout (conflict-free)
#pragma unroll
    for(int s=0; s<2; ++s)
#pragma unroll
    for(int t8=0; t8<8; ++t8){
        int g = t8>>1, hh = t8&1;
        size_t row = (size_t)g*256 + (size_t)w*32 + (size_t)hh*16 + mrow;
        wlds[s][t8][tid] = *(const half8*)(Mdw + row*128 + (6+s)*16 + q16*4);
    }

    // my comps (one per hh) + their gate constants -> registers
    int c0 = w*32 + 0*16 + q16*4 + rsel;
    int c1 = w*32 + 1*16 + q16*4 + rsel;
    float C0[4], C1[4];
#pragma unroll
    for(int g=0; g<4; ++g){
        C0[g] = ws[WS_CV + g*256 + c0];
        C1[g] = ws[WS_CV + g*256 + c1];
    }

    // ---- step 0: h0 = 0, x0 = latent -> gh = bhh ----
    const float* gi = ws + WS_GI0 + (size_t)chain*768;
    float hprev[2];
#pragma unroll
    for(int hh=0; hh<2; ++hh){
        int c = hh ? c1 : c0;
        float r0 = sigf(gi[c] + bhh[c]);
        float z0 = sigf(gi[256+c] + bhh[256+c]);
        float n0 = tanh_fast(gi[512+c] + r0*bhh[512+c]);
        hprev[hh] = (1.0f - z0)*n0;
        if(mrow < 4){
            h16b[0][c] = f2hb(hprev[hh]);
            ws[WS_HSEQ + (size_t)chain*256 + c] = hprev[hh];
        }
    }
    __syncthreads();   // staging + step-0 h visible

    for(int t=1; t<1028; ++t){
        int p = (t-1)&1;
        const char* hbase = (const char*)&h16b[p][0];
#pragma unroll
        for(int hh=0; hh<2; ++hh){
            f32x4 a0={0.f,0.f,0.f,0.f}, a1=a0, a2=a0, a3=a0;
#pragma unroll
            for(int ks=0; ks<8; ++ks){
                half8 hv = *(const half8*)(hbase + ks*64 + q16*16);
                half8 m0 = (ks<6) ? wreg[0][hh][ks] : wlds[ks-6][0*2+hh][tid];
                half8 m1 = (ks<6) ? wreg[1][hh][ks] : wlds[ks-6][1*2+hh][tid];
                half8 m2 = (ks<6) ? wreg[2][hh][ks] : wlds[ks-6][2*2+hh][tid];
                half8 m3 = (ks<6) ? wreg[3][hh][ks] : wlds[ks-6][3*2+hh][tid];
                a0 = __builtin_amdgcn_mfma_f32_16x16x32_f16(m0, hv, a0, 0,0,0);
                a1 = __builtin_amdgcn_mfma_f32_16x16x32_f16(m1, hv, a1, 0,0,0);
                a2 = __builtin_amdgcn_mfma_f32_16x16x32_f16(m2, hv, a2, 0,0,0);
                a3 = __builtin_amdgcn_mfma_f32_16x16x32_f16(m3, hv, a3, 0,0,0);
            }
            // dedup: lane mrow handles acc row rsel=mrow&3 (3 cndmask/gate)
            float s0a = (rsel&1) ? a0[1] : a0[0], s0b = (rsel&1) ? a0[3] : a0[2];
            float s1a = (rsel&1) ? a1[1] : a1[0], s1b = (rsel&1) ? a1[3] : a1[2];
            float s2a = (rsel&1) ? a2[1] : a2[0], s2b = (rsel&1) ? a2[3] : a2[2];
            float s3a = (rsel&1) ? a3[1] : a3[0], s3b = (rsel&1) ? a3[3] : a3[2];
            float s0 = (rsel&2) ? s0b : s0a;
            float s1 = (rsel&2) ? s1b : s1a;
            float s2 = (rsel&2) ? s2b : s2a;
            float s3 = (rsel&2) ? s3b : s3a;
            const float* C = hh ? C1 : C0;
            float rr = sigf(s0 + C[0]);
            float zz = sigf(s1 + C[1]);
            float nn = tanh_fast(s2 + C[2] + rr*(s3 + C[3]));
            hprev[hh] = (1.0f - zz)*nn + zz*hprev[hh];
            if(mrow < 4){
                int c = hh ? c1 : c0;
                h16b[p^1][c] = f2hb(hprev[hh]);
                ws[WS_HSEQ + ((size_t)t*16 + chain)*256 + c] = hprev[hh];
            }
        }
        bar_lgkm();   // new h visible; HSEQ stores ride the vmcnt queue
    }
}

// ======================= epilogue GEMM =====================================
// OUT[b][t*256+j] = sum_c out_W[j][c]*HSEQ[t][b][c] + out_b[j]
__global__ __launch_bounds__(256) void k_epi(const float* outW, const float* outb,
                                             const float* ws, float* out){
    __shared__ float ht[16][256];
    int t = blockIdx.x, j = threadIdx.x;
    for(int idx=j; idx<4096; idx+=256)
        ht[idx>>8][idx&255] = ws[WS_HSEQ + (size_t)t*4096 + idx];
    __syncthreads();
    const float* wr = outW + (size_t)j*256;
    float bias = outb[j];
    float acc[16];
#pragma unroll
    for(int bb=0;bb<16;++bb) acc[bb]=bias;
    for(int k=0;k<256;k+=4){
        float4 w4 = *(const float4*)(wr+k);
#pragma unroll
        for(int bb=0;bb<16;++bb)
            acc[bb] += w4.x*ht[bb][k]+w4.y*ht[bb][k+1]+w4.z*ht[bb][k+2]+w4.w*ht[bb][k+3];
    }
#pragma unroll
    for(int bb=0;bb<16;++bb)
        out[(size_t)bb*263168 + (size_t)t*256 + j] = acc[bb];
}

// ======================= launch ============================================

extern "C" void kernel_launch(void* const* d_in, const int* in_sizes, int n_in,
                              void* d_out, int out_size, void* d_ws, size_t ws_size,
                              hipStream_t stream){
    const float* gs   = (const float*)d_in[0];
    const float* eW   = (const float*)d_in[1];
    const float* eb   = (const float*)d_in[2];
    const float* qkvW = (const float*)d_in[3];
    const float* qkvb = (const float*)d_in[4];
    const float* aoW  = (const float*)d_in[5];
    const float* aob  = (const float*)d_in[6];
    const float* g1   = (const float*)d_in[7];
    const float* b1   = (const float*)d_in[8];
    const float* g2   = (const float*)d_in[9];
    const float* b2   = (const float*)d_in[10];
    const float* W1   = (const float*)d_in[11];
    const float* fb1  = (const float*)d_in[12];
    const float* W2   = (const float*)d_in[13];
    const float* fb2  = (const float*)d_in[14];
    const float* Wih  = (const float*)d_in[15];
    const float* Whh  = (const float*)d_in[16];
    const float* bih  = (const float*)d_in[17];
    const float* bhh  = (const float*)d_in[18];
    const float* outW = (const float*)d_in[19];
    const float* outb = (const float*)d_in[20];
    float* ws  = (float*)d_ws;
    float* out = (float*)d_out;

    k_embed<<<256,256,0,stream>>>(gs,eW,eb,ws);
    for(int l=0;l<2;++l){
        k_qkv    <<<dim3(16,3),256,0,stream>>>(qkvW,qkvb,ws,l);
        k_attn   <<<64,256,0,stream>>>(ws);
        k_ao_ln  <<<256,256,0,stream>>>(aoW,aob,g1,b1,ws,l);
        k_ffn1   <<<dim3(16,4),256,0,stream>>>(W1,fb1,ws,l);
        k_ffn2_ln<<<256,256,0,stream>>>(W2,fb2,g2,b2,ws,l);
    }
    k_latent<<<16,256,0,stream>>>(ws);
    k_gi0   <<<16,768,0,stream>>>(Wih,bih,ws);
    k_prepm <<<1024,256,0,stream>>>(Wih,Whh,bih,bhh,outW,outb,ws);
    k_chain <<<16,512,0,stream>>>(bhh,ws);
    k_epi   <<<1028,256,0,stream>>>(outW,outb,ws,out);
}